// Round 12
// baseline (320.829 us; speedup 1.0000x reference)
//
#include <hip/hip_runtime.h>

// Problem sizes
#define NB  131072   // batch
#define ND1 40       // features (GEMM K)
#define ND2 10       // timesteps
#define NT0 120      // template rows (GEMM M, padded to 128)
#define NT1 5        // u
#define NO0 3        // outputs

#define NBW 32       // batches per workgroup (GEMM N)
#define PK  40       // Ybf row pitch in bf16 elems (80 B, 16B-aligned rows)

typedef __attribute__((ext_vector_type(8))) short  short8;  // 8 bf16 = MFMA A/B frag
typedef __attribute__((ext_vector_type(4))) float  f32x4;   // MFMA C/D frag

static __device__ __forceinline__ unsigned short f2bf(float f) {
    union { float f; unsigned u; } v; v.f = f;
    unsigned r = v.u + 0x7FFFu + ((v.u >> 16) & 1u);   // round-to-nearest-even
    return (unsigned short)(r >> 16);
}

// 2-wave (128-thread) blocks, 32 batches each: smaller barrier convoys and
// ~2.3x more blocks/CU than the 4-wave/64-batch version (latency-bound fix).
//  phase 1 (VALU fp32): y streamed chunk-by-chunk into LDS as bf16.
//  phase 2 (MFMA bf16): wave w owns t-rows [w*64, w*64+64):
//          Z[t,b] = sum_d W11[t,d]*Y_u[d,b]; st += fc4[u]*relu(Z+bias1).
//  epilogue: out[o,b] = sum_t W12[o,t]*st[t,b].
// __launch_bounds__(128,4): 512-reg pool / 4 waves = 128-VGPR cap (the
// proven no-spill tier; live set ~105).
__global__ __launch_bounds__(128, 4) void BL_36721970381090_kernel(
    const float* __restrict__ x,
    const float* __restrict__ W11,
    const float* __restrict__ fc2_w,
    const float* __restrict__ bias1,
    const float* __restrict__ W12,
    const float* __restrict__ fc4_w,
    const float* __restrict__ bias2,
    float* __restrict__ out)
{
    __shared__ __align__(16) unsigned short Ybf[NT1 * NBW * PK];  // 12800 B
    __shared__ float redL[2 * NO0 * NBW];                         //   768 B

    const int tid = threadIdx.x;
    const int wg  = blockIdx.x;

    // ---------------- phase 1: stream y chunks to LDS ---------------------
    {
        const int bl = tid >> 2;                    // batch slot 0..31
        const int q  = tid & 3;                     // d-quarter (rows q*10..+9)
        const float* xb = x + (size_t)(wg * NBW + bl) * (ND1 * ND2) + q * 100;
        unsigned* YbfW = (unsigned*)Ybf;
        const int dbase = bl * (PK / 2) + q * 5;    // dword index within u-plane

#pragma unroll
        for (int g = 0; g < 5; ++g) {               // 2 d-rows (20 floats)/chunk
            float4 xv[5];
            const float4* p = (const float4*)(xb + g * 20);
#pragma unroll
            for (int i = 0; i < 5; ++i) xv[i] = p[i];
            const float* xs = (const float*)xv;
#pragma unroll
            for (int u = 0; u < NT1; ++u) {
                float a0 = 0.f, a1 = 0.f;
#pragma unroll
                for (int s = 0; s < ND2; ++s) {
                    const float fw = fc2_w[u * ND2 + s];
                    a0 = fmaf(xs[s], fw, a0);
                    a1 = fmaf(xs[ND2 + s], fw, a1);
                }
                YbfW[u * (NBW * PK / 2) + dbase + g] =
                    (unsigned)f2bf(a0) | ((unsigned)f2bf(a1) << 16);
            }
        }
    }

    // ---------------- A-fragments: W11 -> bf16, masked (t<120, d<40) ------
    const int w  = tid >> 6;    // wave 0..1: t-rows [w*64, w*64+64)
    const int l  = tid & 63;
    const int lr = l & 15;      // A row / B col within 16-tile
    const int lg = l >> 4;      // k-group (8 contiguous k per group)

    short8 afr[4][2];           // [m-tile][k-tile]
#pragma unroll
    for (int mt = 0; mt < 4; ++mt) {
        const int t  = w * 64 + mt * 16 + lr;
        const int tc = t < NT0 ? t : NT0 - 1;
#pragma unroll
        for (int kk = 0; kk < 2; ++kk) {
            const int cb = kk * 32 + lg * 8;        // k-base 0..56
            const int cc = cb <= 32 ? cb : 0;       // clamp (row is 40 wide)
            const float4* pw = (const float4*)(W11 + tc * ND1 + cc);
            const float4 w0 = pw[0], w1 = pw[1];
            const bool v = (t < NT0) && (cb <= 32); // valid cols only
            short8 f;
            f[0] = v ? (short)f2bf(w0.x) : (short)0;
            f[1] = v ? (short)f2bf(w0.y) : (short)0;
            f[2] = v ? (short)f2bf(w0.z) : (short)0;
            f[3] = v ? (short)f2bf(w0.w) : (short)0;
            f[4] = v ? (short)f2bf(w1.x) : (short)0;
            f[5] = v ? (short)f2bf(w1.y) : (short)0;
            f[6] = v ? (short)f2bf(w1.z) : (short)0;
            f[7] = v ? (short)f2bf(w1.w) : (short)0;
            afr[mt][kk] = f;
        }
    }

    __syncthreads();

    // ---------------- phase 2: MFMA + fused relu/fc4 ----------------------
    float st[4][2][4];          // [m-tile][n-tile][reg] = st[t, b] fragments
#pragma unroll
    for (int mt = 0; mt < 4; ++mt)
#pragma unroll
        for (int nt = 0; nt < 2; ++nt)
#pragma unroll
            for (int r = 0; r < 4; ++r) st[mt][nt][r] = 0.f;

    const short8 zfrag = {0, 0, 0, 0, 0, 0, 0, 0};

#pragma unroll
    for (int u = 0; u < NT1; ++u) {
        const float fu = fc4_w[u];                  // wave-uniform scalar
        float bv[4][4];
#pragma unroll
        for (int mt = 0; mt < 4; ++mt)
#pragma unroll
            for (int r = 0; r < 4; ++r) {
                const int t = w * 64 + mt * 16 + lg * 4 + r;
                bv[mt][r] = (t < NT0) ? bias1[t * NT1 + u] : 0.f;
            }
        const unsigned short* Yu = &Ybf[u * (NBW * PK)];
#pragma unroll
        for (int nt = 0; nt < 2; ++nt) {
            const short8 b0 = *(const short8*)&Yu[(nt * 16 + lr) * PK + lg * 8];
            short8 b1 = zfrag;                       // k-tile 1: cols 32..39
            if (lg == 0)                             // only k-group 0 is real
                b1 = *(const short8*)&Yu[(nt * 16 + lr) * PK + 32];
#pragma unroll
            for (int mt = 0; mt < 4; ++mt) {
                f32x4 z = {0.f, 0.f, 0.f, 0.f};
                z = __builtin_amdgcn_mfma_f32_16x16x32_bf16(afr[mt][0], b0, z, 0, 0, 0);
                z = __builtin_amdgcn_mfma_f32_16x16x32_bf16(afr[mt][1], b1, z, 0, 0, 0);
#pragma unroll
                for (int r = 0; r < 4; ++r)
                    st[mt][nt][r] += fu * fmaxf(z[r] + bv[mt][r], 0.f);
            }
        }
    }

    // ---------------- epilogue: out[o,b] = sum_t W12[o,t]*st[t,b] ---------
    float w12v[NO0][4][4];
#pragma unroll
    for (int o = 0; o < NO0; ++o)
#pragma unroll
        for (int mt = 0; mt < 4; ++mt)
#pragma unroll
            for (int r = 0; r < 4; ++r) {
                const int t = w * 64 + mt * 16 + lg * 4 + r;
                w12v[o][mt][r] = (t < NT0) ? W12[o * NT0 + t] : 0.f;
            }

    float po[2][NO0];
#pragma unroll
    for (int nt = 0; nt < 2; ++nt)
#pragma unroll
        for (int o = 0; o < NO0; ++o) {
            float a = 0.f;
#pragma unroll
            for (int mt = 0; mt < 4; ++mt)
#pragma unroll
                for (int r = 0; r < 4; ++r)
                    a = fmaf(w12v[o][mt][r], st[mt][nt][r], a);
            a += __shfl_xor(a, 16, 64);   // reduce over k-groups (t-rows)
            a += __shfl_xor(a, 32, 64);
            po[nt][o] = a;
        }

    if (l < 16) {
#pragma unroll
        for (int nt = 0; nt < 2; ++nt)
#pragma unroll
            for (int o = 0; o < NO0; ++o)
                redL[(w * NO0 + o) * NBW + nt * 16 + l] = po[nt][o];
    }
    __syncthreads();

    if (tid < NO0 * NBW) {                 // 96 threads
        const int o  = tid >> 5;
        const int bc = tid & 31;
        const float s = redL[(0 * NO0 + o) * NBW + bc]
                      + redL[(1 * NO0 + o) * NBW + bc]
                      + bias2[o];
        out[(size_t)(wg * NBW + bc) * NO0 + o] = s;
    }
}

extern "C" void kernel_launch(void* const* d_in, const int* in_sizes, int n_in,
                              void* d_out, int out_size, void* d_ws, size_t ws_size,
                              hipStream_t stream) {
    const float* x      = (const float*)d_in[0];
    const float* W11    = (const float*)d_in[1];
    const float* fc2_w  = (const float*)d_in[2];
    const float* bias1  = (const float*)d_in[3];
    const float* W12    = (const float*)d_in[4];
    const float* fc4_w  = (const float*)d_in[5];
    const float* bias2  = (const float*)d_in[6];
    float* out = (float*)d_out;

    const int blocks = NB / NBW;   // 4096
    BL_36721970381090_kernel<<<blocks, 128, 0, stream>>>(
        x, W11, fc2_w, bias1, W12, fc4_w, bias2, out);
}

// Round 13
// 118.715 us; speedup vs baseline: 2.7025x; 2.7025x over previous
//
#include <hip/hip_runtime.h>

// Problem sizes
#define NB  131072   // batch
#define ND1 40       // features (GEMM K)
#define ND2 10       // timesteps
#define NT0 120      // template rows (GEMM M, padded to 128)
#define NT1 5        // u
#define NO0 3        // outputs

#define NBW 32       // batches per workgroup (GEMM N)
#define PK  40       // Ybf row pitch in bf16 elems (80 B, 16B-aligned rows)

typedef __attribute__((ext_vector_type(8))) short  short8;  // 8 bf16 = MFMA A/B frag
typedef __attribute__((ext_vector_type(4))) float  f32x4;   // MFMA C/D frag

static __device__ __forceinline__ unsigned short f2bf(float f) {
    union { float f; unsigned u; } v; v.f = f;
    unsigned r = v.u + 0x7FFFu + ((v.u >> 16) & 1u);   // round-to-nearest-even
    return (unsigned short)(r >> 16);
}

// 2-wave (128-thread) blocks, 32 batches each.
//  phase 1 (VALU fp32): y streamed chunk-by-chunk into LDS as bf16.
//  phase 2 (MFMA bf16): wave w owns t-rows [w*64, w*64+64):
//          Z[t,b] = sum_d W11[t,d]*Y_u[d,b]; st += fc4[u]*relu(Z+bias1).
//  epilogue: out[o,b] = sum_t W12[o,t]*st[t,b].
//
// VGPR-cap law (measured R9-R12): compiler cap = 256/min_waves_per_EU,
// regardless of block size. (128,4) -> 64-reg cap -> hot-loop spill
// (FETCH 454 MB, 320 us). (128,2) -> 128-reg cap >= ~105 live set -> no
// spill, and HW still packs 4 waves/SIMD at <=128 VGPRs.
__global__ __launch_bounds__(128, 2) void BL_36721970381090_kernel(
    const float* __restrict__ x,
    const float* __restrict__ W11,
    const float* __restrict__ fc2_w,
    const float* __restrict__ bias1,
    const float* __restrict__ W12,
    const float* __restrict__ fc4_w,
    const float* __restrict__ bias2,
    float* __restrict__ out)
{
    __shared__ __align__(16) unsigned short Ybf[NT1 * NBW * PK];  // 12800 B
    __shared__ float redL[2 * NO0 * NBW];                         //   768 B

    const int tid = threadIdx.x;
    const int wg  = blockIdx.x;

    // ---------------- phase 1: stream y chunks to LDS ---------------------
    {
        const int bl = tid >> 2;                    // batch slot 0..31
        const int q  = tid & 3;                     // d-quarter (rows q*10..+9)
        const float* xb = x + (size_t)(wg * NBW + bl) * (ND1 * ND2) + q * 100;
        unsigned* YbfW = (unsigned*)Ybf;
        const int dbase = bl * (PK / 2) + q * 5;    // dword index within u-plane

#pragma unroll
        for (int g = 0; g < 5; ++g) {               // 2 d-rows (20 floats)/chunk
            float4 xv[5];
            const float4* p = (const float4*)(xb + g * 20);
#pragma unroll
            for (int i = 0; i < 5; ++i) xv[i] = p[i];
            const float* xs = (const float*)xv;
#pragma unroll
            for (int u = 0; u < NT1; ++u) {
                float a0 = 0.f, a1 = 0.f;
#pragma unroll
                for (int s = 0; s < ND2; ++s) {
                    const float fw = fc2_w[u * ND2 + s];
                    a0 = fmaf(xs[s], fw, a0);
                    a1 = fmaf(xs[ND2 + s], fw, a1);
                }
                YbfW[u * (NBW * PK / 2) + dbase + g] =
                    (unsigned)f2bf(a0) | ((unsigned)f2bf(a1) << 16);
            }
        }
    }

    // ---------------- A-fragments: W11 -> bf16, masked (t<120, d<40) ------
    const int w  = tid >> 6;    // wave 0..1: t-rows [w*64, w*64+64)
    const int l  = tid & 63;
    const int lr = l & 15;      // A row / B col within 16-tile
    const int lg = l >> 4;      // k-group (8 contiguous k per group)

    short8 afr[4][2];           // [m-tile][k-tile]
#pragma unroll
    for (int mt = 0; mt < 4; ++mt) {
        const int t  = w * 64 + mt * 16 + lr;
        const int tc = t < NT0 ? t : NT0 - 1;
#pragma unroll
        for (int kk = 0; kk < 2; ++kk) {
            const int cb = kk * 32 + lg * 8;        // k-base 0..56
            const int cc = cb <= 32 ? cb : 0;       // clamp (row is 40 wide)
            const float4* pw = (const float4*)(W11 + tc * ND1 + cc);
            const float4 w0 = pw[0], w1 = pw[1];
            const bool v = (t < NT0) && (cb <= 32); // valid cols only
            short8 f;
            f[0] = v ? (short)f2bf(w0.x) : (short)0;
            f[1] = v ? (short)f2bf(w0.y) : (short)0;
            f[2] = v ? (short)f2bf(w0.z) : (short)0;
            f[3] = v ? (short)f2bf(w0.w) : (short)0;
            f[4] = v ? (short)f2bf(w1.x) : (short)0;
            f[5] = v ? (short)f2bf(w1.y) : (short)0;
            f[6] = v ? (short)f2bf(w1.z) : (short)0;
            f[7] = v ? (short)f2bf(w1.w) : (short)0;
            afr[mt][kk] = f;
        }
    }

    __syncthreads();

    // ---------------- phase 2: MFMA + fused relu/fc4 ----------------------
    float st[4][2][4];          // [m-tile][n-tile][reg] = st[t, b] fragments
#pragma unroll
    for (int mt = 0; mt < 4; ++mt)
#pragma unroll
        for (int nt = 0; nt < 2; ++nt)
#pragma unroll
            for (int r = 0; r < 4; ++r) st[mt][nt][r] = 0.f;

    const short8 zfrag = {0, 0, 0, 0, 0, 0, 0, 0};

#pragma unroll
    for (int u = 0; u < NT1; ++u) {
        const float fu = fc4_w[u];                  // wave-uniform scalar
        float bv[4][4];
#pragma unroll
        for (int mt = 0; mt < 4; ++mt)
#pragma unroll
            for (int r = 0; r < 4; ++r) {
                const int t = w * 64 + mt * 16 + lg * 4 + r;
                bv[mt][r] = (t < NT0) ? bias1[t * NT1 + u] : 0.f;
            }
        const unsigned short* Yu = &Ybf[u * (NBW * PK)];
#pragma unroll
        for (int nt = 0; nt < 2; ++nt) {
            const short8 b0 = *(const short8*)&Yu[(nt * 16 + lr) * PK + lg * 8];
            short8 b1 = zfrag;                       // k-tile 1: cols 32..39
            if (lg == 0)                             // only k-group 0 is real
                b1 = *(const short8*)&Yu[(nt * 16 + lr) * PK + 32];
#pragma unroll
            for (int mt = 0; mt < 4; ++mt) {
                f32x4 z = {0.f, 0.f, 0.f, 0.f};
                z = __builtin_amdgcn_mfma_f32_16x16x32_bf16(afr[mt][0], b0, z, 0, 0, 0);
                z = __builtin_amdgcn_mfma_f32_16x16x32_bf16(afr[mt][1], b1, z, 0, 0, 0);
#pragma unroll
                for (int r = 0; r < 4; ++r)
                    st[mt][nt][r] += fu * fmaxf(z[r] + bv[mt][r], 0.f);
            }
        }
    }

    // ---------------- epilogue: out[o,b] = sum_t W12[o,t]*st[t,b] ---------
    float w12v[NO0][4][4];
#pragma unroll
    for (int o = 0; o < NO0; ++o)
#pragma unroll
        for (int mt = 0; mt < 4; ++mt)
#pragma unroll
            for (int r = 0; r < 4; ++r) {
                const int t = w * 64 + mt * 16 + lg * 4 + r;
                w12v[o][mt][r] = (t < NT0) ? W12[o * NT0 + t] : 0.f;
            }

    float po[2][NO0];
#pragma unroll
    for (int nt = 0; nt < 2; ++nt)
#pragma unroll
        for (int o = 0; o < NO0; ++o) {
            float a = 0.f;
#pragma unroll
            for (int mt = 0; mt < 4; ++mt)
#pragma unroll
                for (int r = 0; r < 4; ++r)
                    a = fmaf(w12v[o][mt][r], st[mt][nt][r], a);
            a += __shfl_xor(a, 16, 64);   // reduce over k-groups (t-rows)
            a += __shfl_xor(a, 32, 64);
            po[nt][o] = a;
        }

    if (l < 16) {
#pragma unroll
        for (int nt = 0; nt < 2; ++nt)
#pragma unroll
            for (int o = 0; o < NO0; ++o)
                redL[(w * NO0 + o) * NBW + nt * 16 + l] = po[nt][o];
    }
    __syncthreads();

    if (tid < NO0 * NBW) {                 // 96 threads
        const int o  = tid >> 5;
        const int bc = tid & 31;
        const float s = redL[(0 * NO0 + o) * NBW + bc]
                      + redL[(1 * NO0 + o) * NBW + bc]
                      + bias2[o];
        out[(size_t)(wg * NBW + bc) * NO0 + o] = s;
    }
}

extern "C" void kernel_launch(void* const* d_in, const int* in_sizes, int n_in,
                              void* d_out, int out_size, void* d_ws, size_t ws_size,
                              hipStream_t stream) {
    const float* x      = (const float*)d_in[0];
    const float* W11    = (const float*)d_in[1];
    const float* fc2_w  = (const float*)d_in[2];
    const float* bias1  = (const float*)d_in[3];
    const float* W12    = (const float*)d_in[4];
    const float* fc4_w  = (const float*)d_in[5];
    const float* bias2  = (const float*)d_in[6];
    float* out = (float*)d_out;

    const int blocks = NB / NBW;   // 4096
    BL_36721970381090_kernel<<<blocks, 128, 0, stream>>>(
        x, W11, fc2_w, bias1, W12, fc4_w, bias2, out);
}

// Round 15
// 62.462 us; speedup vs baseline: 5.1364x; 1.9006x over previous
//
#include <hip/hip_runtime.h>

// Problem sizes
#define NB  131072   // batch
#define ND1 40       // features (GEMM K)
#define ND2 10       // timesteps
#define NT0 120      // template rows (GEMM M, padded to 128)
#define NT1 5        // u
#define NO0 3        // outputs

#define NBW 32       // batches per workgroup (GEMM N)
#define PK  40       // Ybf row pitch in bf16 elems (80 B, 16B-aligned rows)

typedef __attribute__((ext_vector_type(8))) short  short8;  // 8 bf16 = MFMA A/B frag
typedef __attribute__((ext_vector_type(4))) float  f32x4;   // MFMA C/D frag
typedef unsigned int u32;

static __device__ __forceinline__ unsigned short f2bf(float f) {
    union { float f; unsigned u; } v; v.f = f;
    unsigned r = v.u + 0x7FFFu + ((v.u >> 16) & 1u);   // round-to-nearest-even
    return (unsigned short)(r >> 16);
}

// 256-thread (4-wave) blocks, 32 batches each.
//  stage:   x tile (51.2 KB) -> LDS via global_load_lds width=16, perfectly
//           coalesced 1KB/wave-instr (kills the 64-lines-per-instr scatter
//           of per-thread row loads — R11's latency/transaction wall).
//  phase 1: each thread computes y for 5 stride-8 d-rows of one batch from
//           LDS (float2 reads), writes bf16 Y[u][b][d] to LDS.
//           (R14 bug: read used bl*100; batch stride is 400 floats.)
//  phase 2: MFMA bf16, wave w owns t-rows [w*32,w*32+32):
//           Z[t,b] = sum_d W11[t,d]*Y_u[d,b]; st += fc4[u]*relu(Z+bias1).
//  epilogue: out[o,b] = sum_t W12[o,t]*st[t,b].
// __launch_bounds__(256,2): proven no-spill tier (cap ~112-116 >= ~95 live).
__global__ __launch_bounds__(256, 2) void BL_36721970381090_kernel(
    const float* __restrict__ x,
    const float* __restrict__ W11,
    const float* __restrict__ fc2_w,
    const float* __restrict__ bias1,
    const float* __restrict__ W12,
    const float* __restrict__ fc4_w,
    const float* __restrict__ bias2,
    float* __restrict__ out)
{
    __shared__ __align__(16) float xs[NBW * ND1 * ND2];          // 12800 f = 51200 B
    __shared__ __align__(16) unsigned short Ybf[NT1 * NBW * PK]; // 12800 B
    __shared__ float redL[4 * NO0 * NBW];                        //  1536 B

    const int tid = threadIdx.x;
    const int wg  = blockIdx.x;
    const int w   = tid >> 6;   // wave 0..3
    const int l   = tid & 63;

    // ---------------- stage: x tile -> LDS, coalesced -------------------
    {
        const char* gbase = (const char*)(x + (size_t)wg * NBW * (ND1 * ND2));
        char* lbase = (char*)xs;
#pragma unroll
        for (int i = 0; i < 13; ++i) {
            const int j = i * 4 + w;                  // wave-uniform chunk id
            if (j < 50) {                             // 50 x 1KB = 51.2 KB
                const float* g = (const float*)(gbase + j * 1024 + l * 16);
                __builtin_amdgcn_global_load_lds(
                    (const u32 __attribute__((address_space(1)))*)g,
                    (u32 __attribute__((address_space(3)))*)(lbase + j * 1024),
                    16, 0, 0);
            }
        }
    }
    __syncthreads();   // drains vmcnt (compiler emits full waitcnt at barrier)

    // ---------------- phase 1: y from LDS, write bf16 Y ------------------
    {
        const int bl = tid >> 3;                     // batch slot 0..31
        const int q  = tid & 7;                      // row set {q+8k}
        float yv[5][NT1];
#pragma unroll
        for (int k = 0; k < 5; ++k) {
            const int r = q + 8 * k;                 // d-row 0..39
            const float2* xr = (const float2*)&xs[bl * (ND1 * ND2) + r * 10];
            const float2 v0 = xr[0], v1 = xr[1], v2 = xr[2], v3 = xr[3], v4 = xr[4];
            const float xv[10] = {v0.x, v0.y, v1.x, v1.y, v2.x,
                                  v2.y, v3.x, v3.y, v4.x, v4.y};
#pragma unroll
            for (int u = 0; u < NT1; ++u) {
                float a = 0.f;
#pragma unroll
                for (int s = 0; s < ND2; ++s)
                    a = fmaf(xv[s], fc2_w[u * ND2 + s], a);
                yv[k][u] = a;
            }
        }
#pragma unroll
        for (int u = 0; u < NT1; ++u)
#pragma unroll
            for (int k = 0; k < 5; ++k)
                Ybf[u * (NBW * PK) + bl * PK + (q + 8 * k)] = f2bf(yv[k][u]);
    }

    // ---------------- A-fragments: W11 -> bf16, masked (t<120, d<40) -----
    const int lr = l & 15;      // A row / B col within 16-tile
    const int lg = l >> 4;      // k-group (8 contiguous k per group)

    short8 afr[2][2];           // [m-tile][k-tile]
#pragma unroll
    for (int mt = 0; mt < 2; ++mt) {
        const int t  = w * 32 + mt * 16 + lr;
        const int tc = t < NT0 ? t : NT0 - 1;
#pragma unroll
        for (int kk = 0; kk < 2; ++kk) {
            const int cb = kk * 32 + lg * 8;        // k-base 0..56
            const int cc = cb <= 32 ? cb : 0;       // clamp (row is 40 wide)
            const float4* pw = (const float4*)(W11 + tc * ND1 + cc);
            const float4 w0 = pw[0], w1 = pw[1];
            const bool v = (t < NT0) && (cb <= 32); // valid cols only
            short8 f;
            f[0] = v ? (short)f2bf(w0.x) : (short)0;
            f[1] = v ? (short)f2bf(w0.y) : (short)0;
            f[2] = v ? (short)f2bf(w0.z) : (short)0;
            f[3] = v ? (short)f2bf(w0.w) : (short)0;
            f[4] = v ? (short)f2bf(w1.x) : (short)0;
            f[5] = v ? (short)f2bf(w1.y) : (short)0;
            f[6] = v ? (short)f2bf(w1.z) : (short)0;
            f[7] = v ? (short)f2bf(w1.w) : (short)0;
            afr[mt][kk] = f;
        }
    }

    __syncthreads();

    // ---------------- phase 2: MFMA + fused relu/fc4 ---------------------
    float st[2][2][4];          // [m-tile][n-tile][reg]
#pragma unroll
    for (int mt = 0; mt < 2; ++mt)
#pragma unroll
        for (int nt = 0; nt < 2; ++nt)
#pragma unroll
            for (int r = 0; r < 4; ++r) st[mt][nt][r] = 0.f;

    const short8 zfrag = {0, 0, 0, 0, 0, 0, 0, 0};

#pragma unroll
    for (int u = 0; u < NT1; ++u) {
        const float fu = fc4_w[u];                  // wave-uniform scalar
        float bv[2][4];
#pragma unroll
        for (int mt = 0; mt < 2; ++mt)
#pragma unroll
            for (int r = 0; r < 4; ++r) {
                const int t = w * 32 + mt * 16 + lg * 4 + r;
                bv[mt][r] = (t < NT0) ? bias1[t * NT1 + u] : 0.f;
            }
        const unsigned short* Yu = &Ybf[u * (NBW * PK)];
#pragma unroll
        for (int nt = 0; nt < 2; ++nt) {
            const short8 b0 = *(const short8*)&Yu[(nt * 16 + lr) * PK + lg * 8];
            short8 b1 = zfrag;                       // k-tile 1: cols 32..39
            if (lg == 0)                             // only k-group 0 is real
                b1 = *(const short8*)&Yu[(nt * 16 + lr) * PK + 32];
#pragma unroll
            for (int mt = 0; mt < 2; ++mt) {
                f32x4 z = {0.f, 0.f, 0.f, 0.f};
                z = __builtin_amdgcn_mfma_f32_16x16x32_bf16(afr[mt][0], b0, z, 0, 0, 0);
                z = __builtin_amdgcn_mfma_f32_16x16x32_bf16(afr[mt][1], b1, z, 0, 0, 0);
#pragma unroll
                for (int r = 0; r < 4; ++r)
                    st[mt][nt][r] += fu * fmaxf(z[r] + bv[mt][r], 0.f);
            }
        }
    }

    // ---------------- epilogue: out[o,b] = sum_t W12[o,t]*st[t,b] --------
    float w12v[NO0][2][4];
#pragma unroll
    for (int o = 0; o < NO0; ++o)
#pragma unroll
        for (int mt = 0; mt < 2; ++mt)
#pragma unroll
            for (int r = 0; r < 4; ++r) {
                const int t = w * 32 + mt * 16 + lg * 4 + r;
                w12v[o][mt][r] = (t < NT0) ? W12[o * NT0 + t] : 0.f;
            }

    float po[2][NO0];
#pragma unroll
    for (int nt = 0; nt < 2; ++nt)
#pragma unroll
        for (int o = 0; o < NO0; ++o) {
            float a = 0.f;
#pragma unroll
            for (int mt = 0; mt < 2; ++mt)
#pragma unroll
                for (int r = 0; r < 4; ++r)
                    a = fmaf(w12v[o][mt][r], st[mt][nt][r], a);
            a += __shfl_xor(a, 16, 64);   // reduce over k-groups (t-rows)
            a += __shfl_xor(a, 32, 64);
            po[nt][o] = a;
        }

    if (l < 16) {
#pragma unroll
        for (int nt = 0; nt < 2; ++nt)
#pragma unroll
            for (int o = 0; o < NO0; ++o)
                redL[(w * NO0 + o) * NBW + nt * 16 + l] = po[nt][o];
    }
    __syncthreads();

    if (tid < NO0 * NBW) {                 // 96 threads
        const int o  = tid >> 5;
        const int bc = tid & 31;
        const float s = redL[(0 * NO0 + o) * NBW + bc]
                      + redL[(1 * NO0 + o) * NBW + bc]
                      + redL[(2 * NO0 + o) * NBW + bc]
                      + redL[(3 * NO0 + o) * NBW + bc]
                      + bias2[o];
        out[(size_t)(wg * NBW + bc) * NO0 + o] = s;
    }
}

extern "C" void kernel_launch(void* const* d_in, const int* in_sizes, int n_in,
                              void* d_out, int out_size, void* d_ws, size_t ws_size,
                              hipStream_t stream) {
    const float* x      = (const float*)d_in[0];
    const float* W11    = (const float*)d_in[1];
    const float* fc2_w  = (const float*)d_in[2];
    const float* bias1  = (const float*)d_in[3];
    const float* W12    = (const float*)d_in[4];
    const float* fc4_w  = (const float*)d_in[5];
    const float* bias2  = (const float*)d_in[6];
    float* out = (float*)d_out;

    const int blocks = NB / NBW;   // 4096
    BL_36721970381090_kernel<<<blocks, 256, 0, stream>>>(
        x, W11, fc2_w, bias1, W12, fc4_w, bias2, out);
}